// Round 9
// baseline (12908.768 us; speedup 1.0000x reference)
//
#include <hip/hip_runtime.h>
#include <math.h>

#define BATCH 512
#define TT    128
#define FF    64
#define UU    1024
#define ZZ    4096
#define OS    32
#define KTOT  1088
#define NCH   17            // K chunks of 64 (chunk 0 = x, 1..16 = h)
#define CROW  72            // A LDS row stride in f16 (64 + 8 pad = 144 B)
#define CBUF  (64 * CROW)   // 4608 f16 = 9216 B per A chunk buffer
#define NKB   68            // k16 blocks per n-tile (1088/16)
#define NBLK  256

typedef _Float16 f16x8 __attribute__((ext_vector_type(8)));
typedef float f32x16 __attribute__((ext_vector_type(16)));

__device__ __forceinline__ float sigf(float x) { return 1.0f / (1.0f + expf(-x)); }

// ---------------------------------------------------------------------------
// W precompute: [Wk;Wr] (1088x4096 fp32) -> f16, gate-interleaved n' = 4u+g,
// fragment-linear: block (nt,b) of 512 f16 at ((nt*68+b)*512), elem
// (lane = ((k>>3)&1)*32 + (n&31), j = k&7). 1 KB = one wave 16B/lane load.
// ---------------------------------------------------------------------------
__global__ __launch_bounds__(256) void wconv(
    const float* __restrict__ Wk, const float* __restrict__ Wr,
    _Float16* __restrict__ WT)
{
    __shared__ float T[32][129];
    const int k0 = blockIdx.x * 32;   // 34
    const int n0 = blockIdx.y * 128;  // 32
    const int u0 = n0 >> 2;
    const int t = threadIdx.x;
    #pragma unroll
    for (int i = 0; i < 16; ++i) {
        int idx = t + i * 256;
        int u = idx & 31, k = (idx >> 5) & 31, g = idx >> 10;
        int krow = k0 + k;
        int col = g * UU + u0 + u;
        float wv = (krow < FF) ? Wk[(size_t)krow * ZZ + col]
                               : Wr[(size_t)(krow - FF) * ZZ + col];
        T[k][u * 4 + g] = wv;
    }
    __syncthreads();
    #pragma unroll
    for (int i = 0; i < 16; ++i) {
        int idx = t + i * 256;
        int k = idx & 31, np = idx >> 5;
        int r = n0 + np, kk = k0 + k;
        size_t o = ((size_t)(r >> 5) * NKB + (kk >> 4)) * 512
                 + (size_t)((((kk >> 3) & 1) * 32 + (r & 31)) * 8 + (kk & 7));
        WT[o] = (_Float16)T[k][np];
    }
}

// ---------------------------------------------------------------------------
// init: zero h0+c (3MB, 768 blocks), convert ALL x [b][t][f]->[t][b][f] f16
// (16384 blocks), zero barrier counter (1 block).
// ---------------------------------------------------------------------------
__global__ __launch_bounds__(256) void init_k(
    uint4* __restrict__ zbase, const float* __restrict__ x0,
    _Float16* __restrict__ xAll, unsigned* __restrict__ ctr)
{
    const int b = blockIdx.x, t = threadIdx.x;
    if (b < 768) {
        zbase[(size_t)b * 256 + t] = make_uint4(0u, 0u, 0u, 0u);
    } else if (b < 768 + 16384) {
        size_t e = (size_t)(b - 768) * 256 + t;        // over [t][b][f]
        int tt = e >> 15, bb = (e >> 6) & 511, f = e & 63;
        xAll[e] = (_Float16)x0[(size_t)bb * (TT * FF) + tt * FF + f];
    } else {
        if (t == 0) *ctr = 0u;
    }
}

// ---------------------------------------------------------------------------
// grid barrier: syncthreads (drains vmcnt/wave) -> agent release (wbl2) ->
// relaxed LLC atomic + spin -> syncthreads -> agent acquire (inv L1/L2).
// Safe: 256 blocks x 512thr @ <=256 VGPR always co-resident on 256 CUs.
// ---------------------------------------------------------------------------
__device__ __forceinline__ void gridbar(unsigned* ctr, unsigned target) {
    __syncthreads();
    __builtin_amdgcn_fence(__ATOMIC_RELEASE, "agent");
    if (threadIdx.x == 0) {
        __hip_atomic_fetch_add(ctr, 1u, __ATOMIC_RELAXED, __HIP_MEMORY_SCOPE_AGENT);
        while (__hip_atomic_load(ctr, __ATOMIC_RELAXED, __HIP_MEMORY_SCOPE_AGENT) < target)
            __builtin_amdgcn_s_sleep(2);
    }
    __syncthreads();
    __builtin_amdgcn_fence(__ATOMIC_ACQUIRE, "agent");
}

// ---------------------------------------------------------------------------
// One LSTM cell step (R8 structure): A reg-staged LDS dbuf w/ raw s_barrier,
// W direct global->VGPR fragment-linear 3-slot pipeline, fused gates.
// ---------------------------------------------------------------------------
__device__ __forceinline__ void cell_step(
    const _Float16* __restrict__ xp,      // rows stride FF
    const _Float16* __restrict__ hin,
    _Float16* __restrict__ hout,
    float* __restrict__ c,
    const _Float16* __restrict__ WT,
    const float* __restrict__ bias,
    char* smem)
{
    _Float16* lds = (_Float16*)smem;
    float* z = (float*)smem;

    const int t = threadIdx.x;
    const int lane = t & 63;
    const int w  = t >> 6;
    const int mw = w >> 2, nw = w & 3;
    const int panel = blockIdx.x & 31, rtile = blockIdx.x >> 5;
    const int n0 = panel * 128, r0 = rtile * 64, u0 = n0 >> 2;
    const int l31 = lane & 31;

    const int srow = t >> 3, sseg = t & 7;
    const _Float16* aAx = xp  + (size_t)(r0 + srow) * FF + sseg * 8;
    const _Float16* aAh = hin + (size_t)(r0 + srow) * UU + sseg * 8;
    const int wA = srow * CROW + sseg * 8;
    uint4 sA[2];

    const _Float16* pW = WT + ((size_t)(panel * 4 + nw) * NKB) * 512 + lane * 8;
    const int fra = (mw * 32 + l31) * CROW + (lane >> 5) * 8;

    f32x16 acc;
    #pragma unroll
    for (int i = 0; i < 16; ++i) acc[i] = 0.f;
    f16x8 wf[3][4];

#define LOADA(ch)                                                              \
    {                                                                          \
        sA[(ch) & 1] = ((ch) == 0) ? *(const uint4*)aAx                        \
                                   : *(const uint4*)(aAh + ((ch) - 1) * 64);   \
    }
#define LOADW(ch)                                                              \
    {                                                                          \
        _Pragma("unroll")                                                      \
        for (int s = 0; s < 4; ++s)                                            \
            wf[(ch) % 3][s] = *(const f16x8*)(pW + ((ch) * 4 + s) * 512);      \
    }
#define WRITEA(ch)                                                             \
    {                                                                          \
        *(uint4*)(lds + ((ch) & 1) * CBUF + wA) = sA[(ch) & 1];                \
    }

    LOADA(0)
    LOADW(0)
    LOADA(1)
    LOADW(1)
    WRITEA(0)

    #pragma unroll
    for (int ch = 0; ch < NCH; ++ch) {
        if (ch + 2 < NCH) { LOADA(ch + 2) LOADW(ch + 2) }
        __builtin_amdgcn_s_waitcnt(0xC07F);   // lgkmcnt(0) only
        __builtin_amdgcn_s_barrier();
        if (ch + 1 < NCH) WRITEA(ch + 1)
        const _Float16* b = lds + (ch & 1) * CBUF;
        #pragma unroll
        for (int s = 0; s < 4; ++s) {
            f16x8 af = *(const f16x8*)(b + fra + s * 16);
            acc = __builtin_amdgcn_mfma_f32_32x32x16_f16(af, wf[ch % 3][s], acc, 0, 0, 0);
        }
    }
#undef LOADA
#undef LOADW
#undef WRITEA

    __syncthreads();

    // C-frag (32x32: col=lane&31, row=(r&3)+8*(r>>2)+4*(lane>>5)) -> z[m][g][u]
    {
        const int nloc = nw * 32 + l31;
        const int gs = (nloc & 3) * 33 + (nloc >> 2);
        const int rbase = mw * 32 + 4 * (lane >> 5);
        #pragma unroll
        for (int r = 0; r < 16; ++r) {
            int m = rbase + (r & 3) + 8 * (r >> 2);
            z[m * 132 + gs] = acc[r];
        }
    }
    __syncthreads();

    // gates
    {
        const int ul = t & 31;
        const int uu = u0 + ul;
        const float bi = bias[uu], bfr = bias[UU + uu];
        const float bg = bias[2 * UU + uu], bo = bias[3 * UU + uu];
        #pragma unroll
        for (int rep = 0; rep < 4; ++rep) {
            int m = (t >> 5) * 4 + rep;
            float zi = z[m * 132 + ul];
            float zf = z[m * 132 + 33 + ul];
            float zg = z[m * 132 + 66 + ul];
            float zo = z[m * 132 + 99 + ul];
            size_t idx = (size_t)(r0 + m) * UU + uu;
            float cn = sigf(zf + bfr) * c[idx] + sigf(zi + bi) * tanhf(zg + bg);
            c[idx] = cn;
            hout[idx] = (_Float16)(sigf(zo + bo) * tanhf(cn));
        }
    }
}

// ---------------------------------------------------------------------------
// dense (blocks 0..63, 8 rows each): pred = h@Wd + bd -> out slice + prF f16
// ---------------------------------------------------------------------------
__device__ __forceinline__ void dense_step(
    const _Float16* __restrict__ hF,
    const float* __restrict__ Wd, const float* __restrict__ bd,
    _Float16* __restrict__ prF, float* __restrict__ outp, char* smem)
{
    float* red = (float*)smem;                 // [8 ks][8 r][64 f] = 16 KB
    const int t = threadIdx.x, f = t & 63, ks = t >> 6;
    const int rbase = blockIdx.x * 8;
    const _Float16* hb = hF + (size_t)rbase * UU + ks * 128;
    const float* wp = Wd + (size_t)(ks * 128) * FF + f;
    float s[8] = {0.f, 0.f, 0.f, 0.f, 0.f, 0.f, 0.f, 0.f};
    #pragma unroll 2
    for (int v = 0; v < 16; ++v) {
        f16x8 a[8];
        #pragma unroll
        for (int r = 0; r < 8; ++r) a[r] = *(const f16x8*)(hb + r * UU + v * 8);
        #pragma unroll
        for (int j = 0; j < 8; ++j) {
            float wv = wp[(size_t)(v * 8 + j) * FF];
            #pragma unroll
            for (int r = 0; r < 8; ++r) s[r] += (float)a[r][j] * wv;
        }
    }
    #pragma unroll
    for (int r = 0; r < 8; ++r) red[(ks * 8 + r) * 64 + f] = s[r];
    __syncthreads();
    {
        const int r = t >> 6;                  // 0..7 (one output per thread)
        float vv = bd[f];
        #pragma unroll
        for (int k = 0; k < 8; ++k) vv += red[(k * 8 + r) * 64 + f];
        outp[(size_t)(rbase + r) * (OS * FF) + f] = vv;
        prF[(rbase + r) * FF + f] = (_Float16)vv;
    }
}

// ---------------------------------------------------------------------------
// Persistent kernel: all 159 cell steps + 32 dense steps, grid barriers.
// ---------------------------------------------------------------------------
__global__ __launch_bounds__(512, 2) void lstm_all(
    const _Float16* __restrict__ xAll, _Float16* __restrict__ hA,
    _Float16* __restrict__ hB, float* __restrict__ c,
    const _Float16* __restrict__ WT, const float* __restrict__ bias,
    const float* __restrict__ Wd, const float* __restrict__ bd,
    _Float16* __restrict__ prF, float* __restrict__ out,
    unsigned* __restrict__ ctr)
{
    __shared__ __align__(16) char smem[64 * 132 * 4];   // 33792 B
    unsigned phase = 0;
    _Float16* hb[2] = {hA, hB};
    int cur = 0;

    #pragma unroll 1
    for (int t = 0; t < TT; ++t) {
        cell_step(xAll + (size_t)t * (BATCH * FF), hb[cur], hb[cur ^ 1], c, WT, bias, smem);
        ++phase; gridbar(ctr, NBLK * phase);
        cur ^= 1;
    }
    if (blockIdx.x < 64) dense_step(hb[cur], Wd, bd, prF, out, smem);
    ++phase; gridbar(ctr, NBLK * phase);

    #pragma unroll 1
    for (int s = 1; s < OS; ++s) {
        cell_step(prF, hb[cur], hb[cur ^ 1], c, WT, bias, smem);
        ++phase; gridbar(ctr, NBLK * phase);
        cur ^= 1;
        if (blockIdx.x < 64) dense_step(hb[cur], Wd, bd, prF, out + (size_t)s * FF, smem);
        ++phase; gridbar(ctr, NBLK * phase);
    }
}

extern "C" void kernel_launch(void* const* d_in, const int* in_sizes, int n_in,
                              void* d_out, int out_size, void* d_ws, size_t ws_size,
                              hipStream_t stream) {
    const float* inputs = (const float*)d_in[0];
    const float* Wk     = (const float*)d_in[1];
    const float* Wr     = (const float*)d_in[2];
    const float* bias   = (const float*)d_in[3];
    const float* Wd     = (const float*)d_in[4];
    const float* bd     = (const float*)d_in[5];
    float* out = (float*)d_out;

    char* ws = (char*)d_ws;
    _Float16* hA   = (_Float16*)(ws);                 // 1 MB  (zeroed)
    float*    cb   = (float*)(ws + 1048576);          // 2 MB  (zeroed)
    _Float16* hB   = (_Float16*)(ws + 3145728);       // 1 MB
    _Float16* WT   = (_Float16*)(ws + 4194304);       // 8,912,896 B
    _Float16* xAll = (_Float16*)(ws + 13107200);      // 8,388,608 B  [t][b][f]
    _Float16* prF  = (_Float16*)(ws + 21495808);      // 64 KB
    unsigned* ctr  = (unsigned*)(ws + 21561344);      // 4 B

    wconv<<<dim3(34, 32), 256, 0, stream>>>(Wk, Wr, WT);
    init_k<<<768 + 16384 + 1, 256, 0, stream>>>((uint4*)ws, inputs, xAll, ctr);

    lstm_all<<<NBLK, 512, 0, stream>>>(xAll, hA, hB, cb, WT, bias, Wd, bd, prF, out, ctr);
}

// Round 10
// 2722.736 us; speedup vs baseline: 4.7411x; 4.7411x over previous
//
#include <hip/hip_runtime.h>
#include <math.h>

#define BATCH 512
#define TT    128
#define FF    64
#define UU    1024
#define ZZ    4096
#define OS    32
#define KTOT  1088
#define NCHW  17            // warmup K chunks of 64 (0 = x, 1..16 = h)
#define NCHD  16            // decode K chunks of 64 (h only, K=1024)
#define CROW  72            // A LDS row stride in f16 (64 + 8 pad = 144 B)
#define CBUF  (64 * CROW)   // 4608 f16 = 9216 B per A chunk buffer
#define NKBW  68            // warmup k16 blocks per n-tile (1088/16)
#define NKBD  64            // decode k16 blocks per n-tile (1024/16)

typedef _Float16 f16x8 __attribute__((ext_vector_type(8)));
typedef float f32x16 __attribute__((ext_vector_type(16)));

__device__ __forceinline__ float sigf(float x) { return 1.0f / (1.0f + expf(-x)); }

// ---------------------------------------------------------------------------
// wconv: [Wk;Wr] (1088x4096 fp32) -> f16 fragment-linear, gate-interleaved
// n' = 4u+g; block (nt,b) of 512 f16 at ((nt*NKBW+b)*512), elem
// (lane = ((k>>3)&1)*32 + (n&31), j = k&7). 1 KB = one wave 16B/lane load.
// ---------------------------------------------------------------------------
__global__ __launch_bounds__(256) void wconv(
    const float* __restrict__ Wk, const float* __restrict__ Wr,
    _Float16* __restrict__ WT)
{
    __shared__ float T[32][129];
    const int k0 = blockIdx.x * 32;   // 34
    const int n0 = blockIdx.y * 128;  // 32
    const int u0 = n0 >> 2;
    const int t = threadIdx.x;
    #pragma unroll
    for (int i = 0; i < 16; ++i) {
        int idx = t + i * 256;
        int u = idx & 31, k = (idx >> 5) & 31, g = idx >> 10;
        int krow = k0 + k;
        int col = g * UU + u0 + u;
        float wv = (krow < FF) ? Wk[(size_t)krow * ZZ + col]
                               : Wr[(size_t)(krow - FF) * ZZ + col];
        T[k][u * 4 + g] = wv;
    }
    __syncthreads();
    #pragma unroll
    for (int i = 0; i < 16; ++i) {
        int idx = t + i * 256;
        int k = idx & 31, np = idx >> 5;
        int r = n0 + np, kk = k0 + k;
        size_t o = ((size_t)(r >> 5) * NKBW + (kk >> 4)) * 512
                 + (size_t)((((kk >> 3) & 1) * 32 + (r & 31)) * 8 + (kk & 7));
        WT[o] = (_Float16)T[k][np];
    }
}

// ---------------------------------------------------------------------------
// wfus: WT2 = Wr + Wd@Wk (1024x4096), fragment-linear f16 (NKBD blocks/n-tile)
// ---------------------------------------------------------------------------
__global__ __launch_bounds__(256) void wfus(
    const float* __restrict__ Wk, const float* __restrict__ Wr,
    const float* __restrict__ Wd, _Float16* __restrict__ WT2)
{
    __shared__ float Wkk[64][128];    // [f][np]
    __shared__ float Wdd[32][65];     // [k][f], padded
    const int k0 = blockIdx.x * 32;   // 32 (u-rows)
    const int n0 = blockIdx.y * 128;  // 32
    const int u0 = n0 >> 2;
    const int t = threadIdx.x;
    #pragma unroll
    for (int i = 0; i < 32; ++i) {
        int idx = t + i * 256;        // 8192 = 64 f x 128 np
        int f = idx >> 7, np = idx & 127;
        int col = (np & 3) * UU + u0 + (np >> 2);
        Wkk[f][np] = Wk[(size_t)f * ZZ + col];
    }
    #pragma unroll
    for (int i = 0; i < 8; ++i) {
        int idx = t + i * 256;        // 2048 = 32 k x 64 f
        int k = idx >> 6, f = idx & 63;
        Wdd[k][f] = Wd[(size_t)(k0 + k) * FF + f];
    }
    __syncthreads();
    #pragma unroll 1
    for (int i = 0; i < 16; ++i) {
        int idx = t + i * 256;
        int k = idx & 31, np = idx >> 5;
        int col = (np & 3) * UU + u0 + (np >> 2);
        float v = Wr[(size_t)(k0 + k) * ZZ + col];
        #pragma unroll
        for (int f = 0; f < 64; ++f) v += Wdd[k][f] * Wkk[f][np];
        int r = n0 + np, kk = k0 + k;
        size_t o = ((size_t)(r >> 5) * NKBD + (kk >> 4)) * 512
                 + (size_t)((((kk >> 3) & 1) * 32 + (r & 31)) * 8 + (kk & 7));
        WT2[o] = (_Float16)v;
    }
}

// bfus: b2 = b + bd@Wk  (4096)
__global__ __launch_bounds__(256) void bfus(
    const float* __restrict__ Wk, const float* __restrict__ b,
    const float* __restrict__ bd, float* __restrict__ b2)
{
    int col = blockIdx.x * 256 + threadIdx.x;
    float v = b[col];
    #pragma unroll 8
    for (int f = 0; f < 64; ++f) v += bd[f] * Wk[(size_t)f * ZZ + col];
    b2[col] = v;
}

// ---------------------------------------------------------------------------
// init: zero h0+c (3MB contiguous), convert x_0 to f16
// ---------------------------------------------------------------------------
__global__ __launch_bounds__(256) void init_k(
    uint4* __restrict__ zbase, const float* __restrict__ x0,
    _Float16* __restrict__ xF)
{
    const int b = blockIdx.x, t = threadIdx.x;
    if (b < 768) {
        zbase[(size_t)b * 256 + t] = make_uint4(0u, 0u, 0u, 0u);
    } else {
        int e = (b - 768) * 256 + t;   // 0..32767
        int bb = e >> 6, f = e & 63;
        xF[e] = (_Float16)x0[(size_t)bb * (TT * FF) + f];
    }
}

// ---------------------------------------------------------------------------
// Warmup cell (R8 structure, W pipeline depth 4): grid (32 panels, 8 rtiles)
// ---------------------------------------------------------------------------
__global__ __launch_bounds__(512, 2) void cell_warm(
    const _Float16* __restrict__ xF, const _Float16* __restrict__ hF,
    _Float16* __restrict__ hFo, float* __restrict__ c,
    const _Float16* __restrict__ WT, const float* __restrict__ bias,
    const float* __restrict__ xnext, _Float16* __restrict__ xnF)
{
    __shared__ __align__(16) char smem[64 * 132 * 4];
    _Float16* lds = (_Float16*)smem;
    float* z = (float*)smem;

    const int t = threadIdx.x;
    const int lane = t & 63;
    const int w  = t >> 6;
    const int mw = w >> 2, nw = w & 3;
    const int n0 = blockIdx.x * 128;
    const int r0 = blockIdx.y * 64;
    const int u0 = n0 >> 2;
    const int l31 = lane & 31;

    const int srow = t >> 3, sseg = t & 7;
    const _Float16* aAx = xF + (size_t)(r0 + srow) * FF + sseg * 8;
    const _Float16* aAh = hF + (size_t)(r0 + srow) * UU + sseg * 8;
    const int wA = srow * CROW + sseg * 8;
    uint4 sA[2];

    const _Float16* pW = WT + ((size_t)(blockIdx.x * 4 + nw) * NKBW) * 512 + lane * 8;
    const int fra = (mw * 32 + l31) * CROW + (lane >> 5) * 8;

    f32x16 acc;
    #pragma unroll
    for (int i = 0; i < 16; ++i) acc[i] = 0.f;
    f16x8 wf[4][4];

#define LOADA(ch)                                                              \
    {                                                                          \
        sA[(ch) & 1] = ((ch) == 0) ? *(const uint4*)aAx                        \
                                   : *(const uint4*)(aAh + ((ch) - 1) * 64);   \
    }
#define LOADW(ch)                                                              \
    {                                                                          \
        _Pragma("unroll")                                                      \
        for (int s = 0; s < 4; ++s)                                            \
            wf[(ch) & 3][s] = *(const f16x8*)(pW + ((ch) * 4 + s) * 512);      \
    }
#define WRITEA(ch)                                                             \
    {                                                                          \
        *(uint4*)(lds + ((ch) & 1) * CBUF + wA) = sA[(ch) & 1];                \
    }

    LOADA(0) LOADW(0)
    LOADA(1) LOADW(1) LOADW(2)
    WRITEA(0)

    #pragma unroll
    for (int ch = 0; ch < NCHW; ++ch) {
        if (ch + 2 < NCHW) LOADA(ch + 2)
        if (ch + 3 < NCHW) LOADW(ch + 3)
        __builtin_amdgcn_s_waitcnt(0xC07F);   // lgkmcnt(0) only
        __builtin_amdgcn_s_barrier();
        if (ch + 1 < NCHW) WRITEA(ch + 1)
        const _Float16* b = lds + (ch & 1) * CBUF;
        #pragma unroll
        for (int s = 0; s < 4; ++s) {
            f16x8 af = *(const f16x8*)(b + fra + s * 16);
            acc = __builtin_amdgcn_mfma_f32_32x32x16_f16(af, wf[ch & 3][s], acc, 0, 0, 0);
        }
    }
#undef LOADA
#undef LOADW
#undef WRITEA

    __syncthreads();
    {
        const int nloc = nw * 32 + l31;
        const int gs = (nloc & 3) * 33 + (nloc >> 2);
        const int rbase = mw * 32 + 4 * (lane >> 5);
        #pragma unroll
        for (int r = 0; r < 16; ++r) {
            int m = rbase + (r & 3) + 8 * (r >> 2);
            z[m * 132 + gs] = acc[r];
        }
    }
    __syncthreads();
    {
        const int ul = t & 31;
        const int uu = u0 + ul;
        const float bi = bias[uu], bfr = bias[UU + uu];
        const float bg = bias[2 * UU + uu], bo = bias[3 * UU + uu];
        #pragma unroll
        for (int rep = 0; rep < 4; ++rep) {
            int m = (t >> 5) * 4 + rep;
            float zi = z[m * 132 + ul];
            float zf = z[m * 132 + 33 + ul];
            float zg = z[m * 132 + 66 + ul];
            float zo = z[m * 132 + 99 + ul];
            size_t idx = (size_t)(r0 + m) * UU + uu;
            float cn = sigf(zf + bfr) * c[idx] + sigf(zi + bi) * tanhf(zg + bg);
            c[idx] = cn;
            hFo[idx] = (_Float16)(sigf(zo + bo) * tanhf(cn));
        }
    }
    if (xnext != nullptr && t < 128) {
        int e = (blockIdx.x + 32 * blockIdx.y) * 128 + t;
        int bb = e >> 6, f = e & 63;
        xnF[e] = (_Float16)xnext[(size_t)bb * (TT * FF) + f];
    }
}

// ---------------------------------------------------------------------------
// dense: 8 rows per block, 512 thr; out[r][f] = h[r]@Wd + bd (fp32 out only)
// ---------------------------------------------------------------------------
__device__ __forceinline__ void dense_step(
    const _Float16* __restrict__ hF, const float* __restrict__ Wd,
    const float* __restrict__ bd, float* __restrict__ outp,
    char* smem, int rbase)
{
    float* red = (float*)smem;                 // 8 ks x 8 r x 64 f = 16 KB
    const int t = threadIdx.x, f = t & 63, ks = t >> 6;
    const _Float16* hb = hF + (size_t)rbase * UU + ks * 128;
    const float* wp = Wd + (size_t)(ks * 128) * FF + f;
    float s[8] = {0.f, 0.f, 0.f, 0.f, 0.f, 0.f, 0.f, 0.f};
    #pragma unroll 2
    for (int v = 0; v < 16; ++v) {
        f16x8 a[8];
        #pragma unroll
        for (int r = 0; r < 8; ++r) a[r] = *(const f16x8*)(hb + r * UU + v * 8);
        #pragma unroll
        for (int j = 0; j < 8; ++j) {
            float wv = wp[(size_t)(v * 8 + j) * FF];
            #pragma unroll
            for (int r = 0; r < 8; ++r) s[r] += (float)a[r][j] * wv;
        }
    }
    #pragma unroll
    for (int r = 0; r < 8; ++r) red[(ks * 8 + r) * 64 + f] = s[r];
    __syncthreads();
    {
        const int r = t >> 6;
        float vv = bd[f];
        #pragma unroll
        for (int k = 0; k < 8; ++k) vv += red[(k * 8 + r) * 64 + f];
        outp[(size_t)(rbase + r) * (OS * FF) + f] = vv;
    }
}

// ---------------------------------------------------------------------------
// Decode cell: z = h @ (Wr + Wd*Wk) + bfus, K=1024; grid 320 blocks:
// 0..255 cell (panel=bid&31, rtile=bid>>5), 256..319 dense(h_in)->out slice.
// ---------------------------------------------------------------------------
__global__ __launch_bounds__(512, 2) void cell_dec(
    const _Float16* __restrict__ hF, _Float16* __restrict__ hFo,
    float* __restrict__ c, const _Float16* __restrict__ WT2,
    const float* __restrict__ b2, const float* __restrict__ Wd,
    const float* __restrict__ bd, float* __restrict__ outp)
{
    __shared__ __align__(16) char smem[64 * 132 * 4];
    if (blockIdx.x >= 256) {
        dense_step(hF, Wd, bd, outp, smem, (blockIdx.x - 256) * 8);
        return;
    }
    _Float16* lds = (_Float16*)smem;
    float* z = (float*)smem;

    const int t = threadIdx.x;
    const int lane = t & 63;
    const int w  = t >> 6;
    const int mw = w >> 2, nw = w & 3;
    const int panel = blockIdx.x & 31, rtile = blockIdx.x >> 5;
    const int n0 = panel * 128, r0 = rtile * 64, u0 = n0 >> 2;
    const int l31 = lane & 31;

    const int srow = t >> 3, sseg = t & 7;
    const _Float16* aAh = hF + (size_t)(r0 + srow) * UU + sseg * 8;
    const int wA = srow * CROW + sseg * 8;
    uint4 sA[2];

    const _Float16* pW = WT2 + ((size_t)(panel * 4 + nw) * NKBD) * 512 + lane * 8;
    const int fra = (mw * 32 + l31) * CROW + (lane >> 5) * 8;

    f32x16 acc;
    #pragma unroll
    for (int i = 0; i < 16; ++i) acc[i] = 0.f;
    f16x8 wf[4][4];

#define LOADA(ch)  { sA[(ch) & 1] = *(const uint4*)(aAh + (ch) * 64); }
#define LOADW(ch)                                                              \
    {                                                                          \
        _Pragma("unroll")                                                      \
        for (int s = 0; s < 4; ++s)                                            \
            wf[(ch) & 3][s] = *(const f16x8*)(pW + ((ch) * 4 + s) * 512);      \
    }
#define WRITEA(ch) { *(uint4*)(lds + ((ch) & 1) * CBUF + wA) = sA[(ch) & 1]; }

    LOADA(0) LOADW(0)
    LOADA(1) LOADW(1) LOADW(2)
    WRITEA(0)

    #pragma unroll
    for (int ch = 0; ch < NCHD; ++ch) {
        if (ch + 2 < NCHD) LOADA(ch + 2)
        if (ch + 3 < NCHD) LOADW(ch + 3)
        __builtin_amdgcn_s_waitcnt(0xC07F);   // lgkmcnt(0) only
        __builtin_amdgcn_s_barrier();
        if (ch + 1 < NCHD) WRITEA(ch + 1)
        const _Float16* b = lds + (ch & 1) * CBUF;
        #pragma unroll
        for (int s = 0; s < 4; ++s) {
            f16x8 af = *(const f16x8*)(b + fra + s * 16);
            acc = __builtin_amdgcn_mfma_f32_32x32x16_f16(af, wf[ch & 3][s], acc, 0, 0, 0);
        }
    }
#undef LOADA
#undef LOADW
#undef WRITEA

    __syncthreads();
    {
        const int nloc = nw * 32 + l31;
        const int gs = (nloc & 3) * 33 + (nloc >> 2);
        const int rbase = mw * 32 + 4 * (lane >> 5);
        #pragma unroll
        for (int r = 0; r < 16; ++r) {
            int m = rbase + (r & 3) + 8 * (r >> 2);
            z[m * 132 + gs] = acc[r];
        }
    }
    __syncthreads();
    {
        const int ul = t & 31;
        const int uu = u0 + ul;
        const float bi = b2[uu], bfr = b2[UU + uu];
        const float bg = b2[2 * UU + uu], bo = b2[3 * UU + uu];
        #pragma unroll
        for (int rep = 0; rep < 4; ++rep) {
            int m = (t >> 5) * 4 + rep;
            float zi = z[m * 132 + ul];
            float zf = z[m * 132 + 33 + ul];
            float zg = z[m * 132 + 66 + ul];
            float zo = z[m * 132 + 99 + ul];
            size_t idx = (size_t)(r0 + m) * UU + uu;
            float cn = sigf(zf + bfr) * c[idx] + sigf(zi + bi) * tanhf(zg + bg);
            c[idx] = cn;
            hFo[idx] = (_Float16)(sigf(zo + bo) * tanhf(cn));
        }
    }
}

// final dense for out[OS-1]
__global__ __launch_bounds__(512) void dense_fin(
    const _Float16* __restrict__ hF, const float* __restrict__ Wd,
    const float* __restrict__ bd, float* __restrict__ outp)
{
    __shared__ __align__(16) char smem[16384];
    dense_step(hF, Wd, bd, outp, smem, blockIdx.x * 8);
}

extern "C" void kernel_launch(void* const* d_in, const int* in_sizes, int n_in,
                              void* d_out, int out_size, void* d_ws, size_t ws_size,
                              hipStream_t stream) {
    const float* inputs = (const float*)d_in[0];
    const float* Wk     = (const float*)d_in[1];
    const float* Wr     = (const float*)d_in[2];
    const float* bias   = (const float*)d_in[3];
    const float* Wd     = (const float*)d_in[4];
    const float* bd     = (const float*)d_in[5];
    float* out = (float*)d_out;

    char* ws = (char*)d_ws;
    _Float16* hF0 = (_Float16*)(ws);                  // 1 MB   (zeroed)
    float*    cb  = (float*)(ws + 1048576);           // 2 MB   (zeroed)
    _Float16* hF1 = (_Float16*)(ws + 3145728);        // 1 MB
    _Float16* WT  = (_Float16*)(ws + 4194304);        // 8,912,896 (warm frag)
    _Float16* WT2 = (_Float16*)(ws + 13107200);       // 8,388,608 (fused frag)
    _Float16* x0F = (_Float16*)(ws + 21495808);       // 64 KB
    _Float16* x1F = (_Float16*)(ws + 21561344);       // 64 KB
    float*    b2  = (float*)(ws + 21626880);          // 16 KB

    wconv<<<dim3(34, 32), 256, 0, stream>>>(Wk, Wr, WT);
    wfus<<<dim3(32, 32), 256, 0, stream>>>(Wk, Wr, Wd, WT2);
    bfus<<<16, 256, 0, stream>>>(Wk, bias, bd, b2);
    init_k<<<896, 256, 0, stream>>>((uint4*)ws, inputs, x0F);

    dim3 cgrid(32, 8);
    _Float16 *hc = hF0, *hn = hF1;

    for (int t = 0; t < TT; ++t) {
        const _Float16* xF = (t & 1) ? x1F : x0F;
        _Float16* xnF = (t & 1) ? x0F : x1F;
        const float* xnext = (t < TT - 1) ? (inputs + (size_t)(t + 1) * FF) : nullptr;
        cell_warm<<<cgrid, 512, 0, stream>>>(xF, hc, hn, cb, WT, bias, xnext, xnF);
        _Float16* tp = hc; hc = hn; hn = tp;
    }

    // decode: launch s computes h_s from h_{s-1} and out[s-1] = dense(h_{s-1})
    for (int s = 1; s < OS; ++s) {
        cell_dec<<<320, 512, 0, stream>>>(hc, hn, cb, WT2, b2, Wd, bd,
                                          out + (size_t)(s - 1) * FF);
        _Float16* tp = hc; hc = hn; hn = tp;
    }
    dense_fin<<<64, 512, 0, stream>>>(hc, Wd, bd, out + (size_t)(OS - 1) * FF);
}

// Round 11
// 2675.894 us; speedup vs baseline: 4.8241x; 1.0175x over previous
//
#include <hip/hip_runtime.h>
#include <math.h>

#define BATCH 512
#define TT    128
#define FF    64
#define UU    1024
#define ZZ    4096
#define OS    32
#define KTOT  1088
#define NCHW  17            // warmup K chunks of 64 (0 = x, 1..16 = h)
#define NCHD  16            // decode K chunks of 64 (h only, K=1024)
#define CROW  72            // A LDS row stride in f16 (64 + 8 pad = 144 B)
#define CBUF  (32 * CROW)   // 2304 f16 = 4608 B per A chunk buffer (BM=32)
#define NKBW  68            // warmup k16 blocks per n-tile (1088/16)
#define NKBD  64            // decode k16 blocks per n-tile (1024/16)

typedef _Float16 f16x8 __attribute__((ext_vector_type(8)));
typedef float f32x16 __attribute__((ext_vector_type(16)));

__device__ __forceinline__ float sigf(float x) { return 1.0f / (1.0f + expf(-x)); }

// ---------------------------------------------------------------------------
// wconv: [Wk;Wr] (1088x4096 fp32) -> f16 fragment-linear, gate-interleaved
// n' = 4u+g; block (nt,b) of 512 f16 at ((nt*NKBW+b)*512), elem
// (lane = ((k>>3)&1)*32 + (n&31), j = k&7). 1 KB = one wave 16B/lane load.
// ---------------------------------------------------------------------------
__global__ __launch_bounds__(256) void wconv(
    const float* __restrict__ Wk, const float* __restrict__ Wr,
    _Float16* __restrict__ WT)
{
    __shared__ float T[32][129];
    const int k0 = blockIdx.x * 32;   // 34
    const int n0 = blockIdx.y * 128;  // 32
    const int u0 = n0 >> 2;
    const int t = threadIdx.x;
    #pragma unroll
    for (int i = 0; i < 16; ++i) {
        int idx = t + i * 256;
        int u = idx & 31, k = (idx >> 5) & 31, g = idx >> 10;
        int krow = k0 + k;
        int col = g * UU + u0 + u;
        float wv = (krow < FF) ? Wk[(size_t)krow * ZZ + col]
                               : Wr[(size_t)(krow - FF) * ZZ + col];
        T[k][u * 4 + g] = wv;
    }
    __syncthreads();
    #pragma unroll
    for (int i = 0; i < 16; ++i) {
        int idx = t + i * 256;
        int k = idx & 31, np = idx >> 5;
        int r = n0 + np, kk = k0 + k;
        size_t o = ((size_t)(r >> 5) * NKBW + (kk >> 4)) * 512
                 + (size_t)((((kk >> 3) & 1) * 32 + (r & 31)) * 8 + (kk & 7));
        WT[o] = (_Float16)T[k][np];
    }
}

// ---------------------------------------------------------------------------
// wfus: WT2 = Wr + Wd@Wk (1024x4096), fragment-linear f16 (NKBD blocks/n-tile)
// ---------------------------------------------------------------------------
__global__ __launch_bounds__(256) void wfus(
    const float* __restrict__ Wk, const float* __restrict__ Wr,
    const float* __restrict__ Wd, _Float16* __restrict__ WT2)
{
    __shared__ float Wkk[64][128];    // [f][np]
    __shared__ float Wdd[32][65];     // [k][f], padded
    const int k0 = blockIdx.x * 32;   // 32 (u-rows)
    const int n0 = blockIdx.y * 128;  // 32
    const int u0 = n0 >> 2;
    const int t = threadIdx.x;
    #pragma unroll
    for (int i = 0; i < 32; ++i) {
        int idx = t + i * 256;        // 8192 = 64 f x 128 np
        int f = idx >> 7, np = idx & 127;
        int col = (np & 3) * UU + u0 + (np >> 2);
        Wkk[f][np] = Wk[(size_t)f * ZZ + col];
    }
    #pragma unroll
    for (int i = 0; i < 8; ++i) {
        int idx = t + i * 256;        // 2048 = 32 k x 64 f
        int k = idx >> 6, f = idx & 63;
        Wdd[k][f] = Wd[(size_t)(k0 + k) * FF + f];
    }
    __syncthreads();
    #pragma unroll 1
    for (int i = 0; i < 16; ++i) {
        int idx = t + i * 256;
        int k = idx & 31, np = idx >> 5;
        int col = (np & 3) * UU + u0 + (np >> 2);
        float v = Wr[(size_t)(k0 + k) * ZZ + col];
        #pragma unroll
        for (int f = 0; f < 64; ++f) v += Wdd[k][f] * Wkk[f][np];
        int r = n0 + np, kk = k0 + k;
        size_t o = ((size_t)(r >> 5) * NKBD + (kk >> 4)) * 512
                 + (size_t)((((kk >> 3) & 1) * 32 + (r & 31)) * 8 + (kk & 7));
        WT2[o] = (_Float16)v;
    }
}

// bfus: b2 = b + bd@Wk  (4096)
__global__ __launch_bounds__(256) void bfus(
    const float* __restrict__ Wk, const float* __restrict__ b,
    const float* __restrict__ bd, float* __restrict__ b2)
{
    int col = blockIdx.x * 256 + threadIdx.x;
    float v = b[col];
    #pragma unroll 8
    for (int f = 0; f < 64; ++f) v += bd[f] * Wk[(size_t)f * ZZ + col];
    b2[col] = v;
}

// ---------------------------------------------------------------------------
// init: zero h0+c (3MB contiguous), convert x_0 to f16
// ---------------------------------------------------------------------------
__global__ __launch_bounds__(256) void init_k(
    uint4* __restrict__ zbase, const float* __restrict__ x0,
    _Float16* __restrict__ xF)
{
    const int b = blockIdx.x, t = threadIdx.x;
    if (b < 768) {
        zbase[(size_t)b * 256 + t] = make_uint4(0u, 0u, 0u, 0u);
    } else {
        int e = (b - 768) * 256 + t;   // 0..32767
        int bb = e >> 6, f = e & 63;
        xF[e] = (_Float16)x0[(size_t)bb * (TT * FF) + f];
    }
}

// ---------------------------------------------------------------------------
// Warmup cell: BM=32 x BN'=128, 256 thr = 4 waves (nw = wave id), BK=64.
// A reg-staged LDS dbuf (raw s_barrier + lgkm-only), W direct VGPR 4-slot.
// Grid (32 panels, 16 rtiles) = 512 blocks -> 2 independent blocks/CU.
// ---------------------------------------------------------------------------
__global__ __launch_bounds__(256, 2) void cell_warm(
    const _Float16* __restrict__ xF, const _Float16* __restrict__ hF,
    _Float16* __restrict__ hFo, float* __restrict__ c,
    const _Float16* __restrict__ WT, const float* __restrict__ bias,
    const float* __restrict__ xnext, _Float16* __restrict__ xnF)
{
    __shared__ __align__(16) char smem[32 * 132 * 4];   // 16896 B
    _Float16* lds = (_Float16*)smem;
    float* z = (float*)smem;

    const int t = threadIdx.x;
    const int lane = t & 63;
    const int nw = t >> 6;          // wave 0..3 = n-tile
    const int n0 = blockIdx.x * 128;
    const int r0 = blockIdx.y * 32;
    const int u0 = n0 >> 2;
    const int l31 = lane & 31;

    const int srow = t >> 3, sseg = t & 7;   // A stage: row 0..31, seg 0..7
    const _Float16* aAx = xF + (size_t)(r0 + srow) * FF + sseg * 8;
    const _Float16* aAh = hF + (size_t)(r0 + srow) * UU + sseg * 8;
    const int wA = srow * CROW + sseg * 8;
    uint4 sA[2];

    const _Float16* pW = WT + ((size_t)(blockIdx.x * 4 + nw) * NKBW) * 512 + lane * 8;
    const int fra = l31 * CROW + (lane >> 5) * 8;

    f32x16 acc;
    #pragma unroll
    for (int i = 0; i < 16; ++i) acc[i] = 0.f;
    f16x8 wf[4][4];

#define LOADA(ch)                                                              \
    {                                                                          \
        sA[(ch) & 1] = ((ch) == 0) ? *(const uint4*)aAx                        \
                                   : *(const uint4*)(aAh + ((ch) - 1) * 64);   \
    }
#define LOADW(ch)                                                              \
    {                                                                          \
        _Pragma("unroll")                                                      \
        for (int s = 0; s < 4; ++s)                                            \
            wf[(ch) & 3][s] = *(const f16x8*)(pW + ((ch) * 4 + s) * 512);      \
    }
#define WRITEA(ch)                                                             \
    {                                                                          \
        *(uint4*)(lds + ((ch) & 1) * CBUF + wA) = sA[(ch) & 1];                \
    }

    LOADA(0) LOADW(0)
    LOADA(1) LOADW(1) LOADW(2)
    WRITEA(0)

    #pragma unroll
    for (int ch = 0; ch < NCHW; ++ch) {
        if (ch + 2 < NCHW) LOADA(ch + 2)
        if (ch + 3 < NCHW) LOADW(ch + 3)
        __builtin_amdgcn_s_waitcnt(0xC07F);   // lgkmcnt(0) only
        __builtin_amdgcn_s_barrier();
        if (ch + 1 < NCHW) WRITEA(ch + 1)
        const _Float16* b = lds + (ch & 1) * CBUF;
        #pragma unroll
        for (int s = 0; s < 4; ++s) {
            f16x8 af = *(const f16x8*)(b + fra + s * 16);
            acc = __builtin_amdgcn_mfma_f32_32x32x16_f16(af, wf[ch & 3][s], acc, 0, 0, 0);
        }
    }
#undef LOADA
#undef LOADW
#undef WRITEA

    __syncthreads();
    {   // C-frag (col=lane&31, row=(r&3)+8*(r>>2)+4*(lane>>5)) -> z[m][g][u]
        const int nloc = nw * 32 + l31;
        const int gs = (nloc & 3) * 33 + (nloc >> 2);
        const int rbase = 4 * (lane >> 5);
        #pragma unroll
        for (int r = 0; r < 16; ++r) {
            int m = rbase + (r & 3) + 8 * (r >> 2);
            z[m * 132 + gs] = acc[r];
        }
    }
    __syncthreads();
    {   // gates: thread (u = t&31), 4 m-rows each
        const int ul = t & 31;
        const int uu = u0 + ul;
        const float bi = bias[uu], bfr = bias[UU + uu];
        const float bg = bias[2 * UU + uu], bo = bias[3 * UU + uu];
        #pragma unroll
        for (int rep = 0; rep < 4; ++rep) {
            int m = (t >> 5) * 4 + rep;
            float zi = z[m * 132 + ul];
            float zf = z[m * 132 + 33 + ul];
            float zg = z[m * 132 + 66 + ul];
            float zo = z[m * 132 + 99 + ul];
            size_t idx = (size_t)(r0 + m) * UU + uu;
            float cn = sigf(zf + bfr) * c[idx] + sigf(zi + bi) * tanhf(zg + bg);
            c[idx] = cn;
            hFo[idx] = (_Float16)(sigf(zo + bo) * tanhf(cn));
        }
    }
    // convert next warmup x slice (512 blocks x 64 = 32768 elems)
    if (xnext != nullptr && t < 64) {
        int e = (blockIdx.x + 32 * blockIdx.y) * 64 + t;
        int bb = e >> 6, f = e & 63;
        xnF[e] = (_Float16)xnext[(size_t)bb * (TT * FF) + f];
    }
}

// ---------------------------------------------------------------------------
// dense (256 thr): 8 rows/block; out[r][f] = h[r]@Wd + bd (fp32 out only)
// ---------------------------------------------------------------------------
__device__ __forceinline__ void dense_step(
    const _Float16* __restrict__ hF, const float* __restrict__ Wd,
    const float* __restrict__ bd, float* __restrict__ outp,
    char* smem, int rbase)
{
    float* red = (float*)smem;                 // 4 ks x 8 r x 64 f = 8 KB
    const int t = threadIdx.x, f = t & 63, ks = t >> 6;   // ks 0..3
    const _Float16* hb = hF + (size_t)rbase * UU + ks * 256;
    const float* wp = Wd + (size_t)(ks * 256) * FF + f;
    float s[8] = {0.f, 0.f, 0.f, 0.f, 0.f, 0.f, 0.f, 0.f};
    #pragma unroll 2
    for (int v = 0; v < 32; ++v) {
        f16x8 a[8];
        #pragma unroll
        for (int r = 0; r < 8; ++r) a[r] = *(const f16x8*)(hb + r * UU + v * 8);
        #pragma unroll
        for (int j = 0; j < 8; ++j) {
            float wv = wp[(size_t)(v * 8 + j) * FF];
            #pragma unroll
            for (int r = 0; r < 8; ++r) s[r] += (float)a[r][j] * wv;
        }
    }
    #pragma unroll
    for (int r = 0; r < 8; ++r) red[(ks * 8 + r) * 64 + f] = s[r];
    __syncthreads();
    {
        const int q = t >> 6;                  // 0..3 -> rows q and q+4
        #pragma unroll
        for (int h = 0; h < 2; ++h) {
            int r = q + h * 4;
            float vv = bd[f];
            #pragma unroll
            for (int k = 0; k < 4; ++k) vv += red[(k * 8 + r) * 64 + f];
            outp[(size_t)(rbase + r) * (OS * FF) + f] = vv;
        }
    }
}

// ---------------------------------------------------------------------------
// Decode cell: z = h @ (Wr + Wd*Wk) + bfus, K=1024. Grid 576 blocks:
// 0..511 cell (panel=bid&31, rtile=bid>>5), 512..575 dense(h_in)->out slice.
// ---------------------------------------------------------------------------
__global__ __launch_bounds__(256, 2) void cell_dec(
    const _Float16* __restrict__ hF, _Float16* __restrict__ hFo,
    float* __restrict__ c, const _Float16* __restrict__ WT2,
    const float* __restrict__ b2, const float* __restrict__ Wd,
    const float* __restrict__ bd, float* __restrict__ outp)
{
    __shared__ __align__(16) char smem[32 * 132 * 4];
    if (blockIdx.x >= 512) {
        dense_step(hF, Wd, bd, outp, smem, (blockIdx.x - 512) * 8);
        return;
    }
    _Float16* lds = (_Float16*)smem;
    float* z = (float*)smem;

    const int t = threadIdx.x;
    const int lane = t & 63;
    const int nw = t >> 6;
    const int panel = blockIdx.x & 31, rtile = blockIdx.x >> 5;
    const int n0 = panel * 128, r0 = rtile * 32, u0 = n0 >> 2;
    const int l31 = lane & 31;

    const int srow = t >> 3, sseg = t & 7;
    const _Float16* aAh = hF + (size_t)(r0 + srow) * UU + sseg * 8;
    const int wA = srow * CROW + sseg * 8;
    uint4 sA[2];

    const _Float16* pW = WT2 + ((size_t)(panel * 4 + nw) * NKBD) * 512 + lane * 8;
    const int fra = l31 * CROW + (lane >> 5) * 8;

    f32x16 acc;
    #pragma unroll
    for (int i = 0; i < 16; ++i) acc[i] = 0.f;
    f16x8 wf[4][4];

#define LOADA(ch)  { sA[(ch) & 1] = *(const uint4*)(aAh + (ch) * 64); }
#define LOADW(ch)                                                              \
    {                                                                          \
        _Pragma("unroll")                                                      \
        for (int s = 0; s < 4; ++s)                                            \
            wf[(ch) & 3][s] = *(const f16x8*)(pW + ((ch) * 4 + s) * 512);      \
    }
#define WRITEA(ch) { *(uint4*)(lds + ((ch) & 1) * CBUF + wA) = sA[(ch) & 1]; }

    LOADA(0) LOADW(0)
    LOADA(1) LOADW(1) LOADW(2)
    WRITEA(0)

    #pragma unroll
    for (int ch = 0; ch < NCHD; ++ch) {
        if (ch + 2 < NCHD) LOADA(ch + 2)
        if (ch + 3 < NCHD) LOADW(ch + 3)
        __builtin_amdgcn_s_waitcnt(0xC07F);   // lgkmcnt(0) only
        __builtin_amdgcn_s_barrier();
        if (ch + 1 < NCHD) WRITEA(ch + 1)
        const _Float16* b = lds + (ch & 1) * CBUF;
        #pragma unroll
        for (int s = 0; s < 4; ++s) {
            f16x8 af = *(const f16x8*)(b + fra + s * 16);
            acc = __builtin_amdgcn_mfma_f32_32x32x16_f16(af, wf[ch & 3][s], acc, 0, 0, 0);
        }
    }
#undef LOADA
#undef LOADW
#undef WRITEA

    __syncthreads();
    {
        const int nloc = nw * 32 + l31;
        const int gs = (nloc & 3) * 33 + (nloc >> 2);
        const int rbase = 4 * (lane >> 5);
        #pragma unroll
        for (int r = 0; r < 16; ++r) {
            int m = rbase + (r & 3) + 8 * (r >> 2);
            z[m * 132 + gs] = acc[r];
        }
    }
    __syncthreads();
    {
        const int ul = t & 31;
        const int uu = u0 + ul;
        const float bi = b2[uu], bfr = b2[UU + uu];
        const float bg = b2[2 * UU + uu], bo = b2[3 * UU + uu];
        #pragma unroll
        for (int rep = 0; rep < 4; ++rep) {
            int m = (t >> 5) * 4 + rep;
            float zi = z[m * 132 + ul];
            float zf = z[m * 132 + 33 + ul];
            float zg = z[m * 132 + 66 + ul];
            float zo = z[m * 132 + 99 + ul];
            size_t idx = (size_t)(r0 + m) * UU + uu;
            float cn = sigf(zf + bfr) * c[idx] + sigf(zi + bi) * tanhf(zg + bg);
            c[idx] = cn;
            hFo[idx] = (_Float16)(sigf(zo + bo) * tanhf(cn));
        }
    }
}

// final dense for out[OS-1]
__global__ __launch_bounds__(256) void dense_fin(
    const _Float16* __restrict__ hF, const float* __restrict__ Wd,
    const float* __restrict__ bd, float* __restrict__ outp)
{
    __shared__ __align__(16) char smem[8192];
    dense_step(hF, Wd, bd, outp, smem, blockIdx.x * 8);
}

extern "C" void kernel_launch(void* const* d_in, const int* in_sizes, int n_in,
                              void* d_out, int out_size, void* d_ws, size_t ws_size,
                              hipStream_t stream) {
    const float* inputs = (const float*)d_in[0];
    const float* Wk     = (const float*)d_in[1];
    const float* Wr     = (const float*)d_in[2];
    const float* bias   = (const float*)d_in[3];
    const float* Wd     = (const float*)d_in[4];
    const float* bd     = (const float*)d_in[5];
    float* out = (float*)d_out;

    char* ws = (char*)d_ws;
    _Float16* hF0 = (_Float16*)(ws);                  // 1 MB   (zeroed)
    float*    cb  = (float*)(ws + 1048576);           // 2 MB   (zeroed)
    _Float16* hF1 = (_Float16*)(ws + 3145728);        // 1 MB
    _Float16* WT  = (_Float16*)(ws + 4194304);        // 8,912,896 (warm frag)
    _Float16* WT2 = (_Float16*)(ws + 13107200);       // 8,388,608 (fused frag)
    _Float16* x0F = (_Float16*)(ws + 21495808);       // 64 KB
    _Float16* x1F = (_Float16*)(ws + 21561344);       // 64 KB
    float*    b2  = (float*)(ws + 21626880);          // 16 KB

    wconv<<<dim3(34, 32), 256, 0, stream>>>(Wk, Wr, WT);
    wfus<<<dim3(32, 32), 256, 0, stream>>>(Wk, Wr, Wd, WT2);
    bfus<<<16, 256, 0, stream>>>(Wk, bias, bd, b2);
    init_k<<<896, 256, 0, stream>>>((uint4*)ws, inputs, x0F);

    dim3 cgrid(32, 16);   // (panel, rtile) -> 512 blocks, 2/CU
    _Float16 *hc = hF0, *hn = hF1;

    for (int t = 0; t < TT; ++t) {
        const _Float16* xF = (t & 1) ? x1F : x0F;
        _Float16* xnF = (t & 1) ? x0F : x1F;
        const float* xnext = (t < TT - 1) ? (inputs + (size_t)(t + 1) * FF) : nullptr;
        cell_warm<<<cgrid, 256, 0, stream>>>(xF, hc, hn, cb, WT, bias, xnext, xnF);
        _Float16* tp = hc; hc = hn; hn = tp;
    }

    // decode: launch s computes h_s from h_{s-1} and out[s-1] = dense(h_{s-1})
    for (int s = 1; s < OS; ++s) {
        cell_dec<<<576, 256, 0, stream>>>(hc, hn, cb, WT2, b2, Wd, bd,
                                          out + (size_t)(s - 1) * FF);
        _Float16* tp = hc; hc = hn; hn = tp;
    }
    dense_fin<<<64, 256, 0, stream>>>(hc, Wd, bd, out + (size_t)(OS - 1) * FF);
}